// Round 7
// baseline (185.225 us; speedup 1.0000x reference)
//
#include <hip/hip_runtime.h>

#define NBINS 2048
#define B 4
#define C 16
#define HID 32
#define NI 32
#define INTER 36864           // 192*192 interior pixels per image
#define PADMULT 28672         // 256*256 - 192*192 padded pixels per instance
#define EPSF 1e-6f
#define THR 256
#define BPI 144               // blocks per image, 1 pixel/thread
#define NBLK (B * BPI)        // 576 blocks
#define INIT_BLK 64

// ---- ws layout (uint units)
#define OFF_COUNTS 0                      // [B][NI] float
#define OFF_CSUMS  (OFF_COUNTS + B*NI)    // [B][NI][C] float
#define OFF_V      (OFF_CSUMS + B*NI*C)   // [B][NI][HID] float
#define OFF_PERR   (OFF_V + B*NI*HID)     // [B][NI] float
#define OFF_MKEY   (OFF_PERR + B*NI)      // [B] uint: fmap(max ||e||^2)
#define OFF_RANGE  (OFF_MKEY + B)         // [B][2] float: emin, emax
#define OFF_DONE0  (OFF_RANGE + 2*B)      // [B] uint: stats blocks done
#define OFF_DONE1  (OFF_DONE0 + B)        // [B] uint: hist blocks done
#define CTRL_END   (OFF_DONE1 + B)
#define OFF_F64    8192                   // [B][NBINS] u64 (cnt lo32 | pos hi32)

__device__ inline unsigned fmap(float f) {
    unsigned u = __float_as_uint(f);
    return (u & 0x80000000u) ? ~u : (u | 0x80000000u);
}
__device__ inline float funmap(unsigned k) {
    return (k & 0x80000000u) ? __uint_as_float(k & 0x7fffffffu)
                             : __uint_as_float(~k);
}
// Agent-scope atomic loads: consumer side of the last-block pattern.
__device__ inline float aload_f(const float* p) {
    return __hip_atomic_load(p, __ATOMIC_RELAXED, __HIP_MEMORY_SCOPE_AGENT);
}
__device__ inline unsigned aload_u(const unsigned* p) {
    return __hip_atomic_load(p, __ATOMIC_RELAXED, __HIP_MEMORY_SCOPE_AGENT);
}
__device__ inline unsigned long long aload_u64(const unsigned long long* p) {
    return __hip_atomic_load(p, __ATOMIC_RELAXED, __HIP_MEMORY_SCOPE_AGENT);
}

// k_init: zero control words + F64 histogram + out. 64 blocks, ~2 us.
__global__ void k_init(unsigned* wsu, float* out) {
    unsigned gtid = blockIdx.x * 256u + threadIdx.x;
    for (unsigned i = gtid; i < CTRL_END; i += INIT_BLK * 256u) wsu[i] = 0u;
    unsigned* f = wsu + OFF_F64;
    for (unsigned i = gtid; i < B * NBINS * 2; i += INIT_BLK * 256u) f[i] = 0u;
    if (gtid == 0) out[0] = 0.f;
}

// k_stats: per-instance counts & weighted embedding sums + max ||e||^2,
// then the LAST block of each image computes centers/V/range inline.
__global__ __launch_bounds__(THR, 4) void k_stats(
        const float* __restrict__ emb, const float* __restrict__ wgt,
        const int* __restrict__ gt, const float* __restrict__ W1,
        const float* __restrict__ b1, const float* __restrict__ W2,
        const float* __restrict__ b2, float* ws, unsigned* wsu) {
    struct SSt { float cnt[NI]; float sum[NI * 17]; };  // stride 17: bank split
    struct SCt { float v[NI * HID]; float a[HID]; float stage[NI * (C + 1)]; };
    __shared__ union { SSt st; SCt ct; } sm;
    __shared__ unsigned s_mk, s_lo, s_hi;
    __shared__ int s_last;
    int tid = threadIdx.x, bx = blockIdx.x;
    int img = bx / BPI;
    int q = (bx - img * BPI) * THR + tid;
    for (int i = tid; i < NI; i += THR) sm.st.cnt[i] = 0.f;
    for (int i = tid; i < NI * 17; i += THR) sm.st.sum[i] = 0.f;
    if (tid == 0) s_mk = 0u;
    __syncthreads();

    int g = gt[img * INTER + q];
    const float* ep = emb + (size_t)img * C * INTER + q;
    float e[C];
    float nrm = 0.f;
    #pragma unroll
    for (int c = 0; c < C; c++) { e[c] = ep[c * INTER]; nrm = fmaf(e[c], e[c], nrm); }
    if (g > 0) {
        float wv = wgt[img * INTER + q];
        atomicAdd(&sm.st.cnt[g - 1], wv);
        #pragma unroll
        for (int c = 0; c < C; c++)
            atomicAdd(&sm.st.sum[(g - 1) * 17 + c], e[c] * wv);
    }
    atomicMax(&s_mk, fmap(nrm));
    __syncthreads();
    for (int i = tid; i < NI; i += THR)
        atomicAdd(&ws[OFF_COUNTS + img * NI + i], sm.st.cnt[i]);
    for (int i = tid; i < NI * C; i += THR) {
        int n = i / C, c = i - n * C;
        atomicAdd(&ws[OFF_CSUMS + (img * NI + n) * C + c], sm.st.sum[n * 17 + c]);
    }
    if (tid == 0) atomicMax(&wsu[OFF_MKEY + img], s_mk);

    // ---- last-block detection (release: each thread fences its own atomics)
    __threadfence();
    __syncthreads();
    if (tid == 0)
        s_last = (atomicAdd(&wsu[OFF_DONE0 + img], 1u) == (unsigned)(BPI - 1));
    __syncthreads();
    if (!s_last) return;

    // ---- centers tail: one block per image, stats guaranteed complete
    int im = img;
    for (int i = tid; i < NI * (C + 1); i += THR) {
        float v = (i < NI) ? aload_f(&ws[OFF_COUNTS + im * NI + i])
                           : aload_f(&ws[OFF_CSUMS + im * NI * C + (i - NI)]);
        sm.ct.stage[i] = v;   // [0,NI) counts, [NI..) csums row-major
    }
    float b2v = b2[0];
    float M = sqrtf(funmap(aload_u(&wsu[OFF_MKEY + im])));
    if (tid < HID) {
        float ssq = 0.f;
        #pragma unroll
        for (int c = 0; c < C; c++)
            ssq = fmaf(W1[c * HID + tid], W1[c * HID + tid], ssq);
        sm.ct.a[tid] = M * sqrtf(ssq);
    }
    if (tid == 0) { s_lo = 0xFFFFFFFFu; s_hi = 0u; }
    __syncthreads();
    for (int idx = tid; idx < NI * HID; idx += THR) {
        int n = idx >> 5, k = idx & 31;
        float cv = sm.ct.stage[n] + EPSF;
        float acc = b1[k];
        #pragma unroll
        for (int c = 0; c < C; c++)
            acc += (sm.ct.stage[NI + n * C + c] / cv) * W1[c * HID + k];
        sm.ct.v[idx] = acc;
        ws[OFF_V + im * NI * HID + idx] = acc;   // next-kernel visibility
    }
    __syncthreads();
    if (tid < NI) {
        float lo = b2v, hi = b2v, lgp = b2v;
        #pragma unroll
        for (int k = 0; k < HID; k++) {
            float vk = sm.ct.v[tid * HID + k], a = sm.ct.a[k], w = W2[k];
            float thi = fmaxf(vk + a, 0.f), tlo = fmaxf(vk - a, 0.f);
            hi += w * (w > 0.f ? thi : tlo);
            lo += w * (w > 0.f ? tlo : thi);
            lgp = fmaf(fmaxf(vk, 0.f), w, lgp);   // pad pixels: u = 0 exact
        }
        float pe = 1.f + lgp;
        ws[OFF_PERR + im * NI + tid] = pe;
        atomicMin(&s_lo, fmap(fminf(1.f - hi, 1.f + lo)));
        atomicMax(&s_hi, fmap(fmaxf(1.f - lo, 1.f + hi)));
    }
    __syncthreads();
    if (tid == 0) {
        ((float*)wsu)[OFF_RANGE + im * 2]     = funmap(s_lo);
        ((float*)wsu)[OFF_RANGE + im * 2 + 1] = funmap(s_hi);
    }
}

// k_hist: R2-proven main loop restored -- vn[] via wave-uniform scalar
// loads (SMEM pipe, SGPR destinations: zero LDS contention, zero VGPR
// cost; the n-loop unroll-4 hides the ~200cy s_load latency). R5's
// V-in-LDS variant put the V reads on the already-hot LDS pipe and
// +32 live VGPRs -> spill, 61.7us. Main-phase LDS is the 8KB histogram
// only; the loss tail (last block per image) uses its own union arm.
struct SMemLoss { unsigned cnt[NBINS]; unsigned pos[NBINS]; float sum[NBINS];
                  unsigned pc[THR]; unsigned pp[THR]; double a[THR]; };

__global__ __launch_bounds__(THR, 4) void k_hist(
        const float* __restrict__ emb, const int* __restrict__ gt,
        const float* __restrict__ W1, const float* __restrict__ W2,
        const float* __restrict__ b2, const float* __restrict__ ws,
        unsigned* wsu, float* out) {
    __shared__ union { unsigned h[NBINS]; SMemLoss ls; } sm;   // 28 KB
    __shared__ int s_last;
    int tid = threadIdx.x, bx = blockIdx.x;
    int img = bx / BPI;
    int q = (bx - img * BPI) * THR + tid;
    for (int i = tid; i < NBINS; i += THR) sm.h[i] = 0u;
    float emin = ((const float*)wsu)[OFF_RANGE + img * 2];
    float emax = ((const float*)wsu)[OFF_RANGE + img * 2 + 1];
    float invbw = (float)NBINS / fmaxf(emax - emin, 1e-20f);
    float b2v = b2[0];
    const float* vimg = ws + OFF_V + img * NI * HID;   // wave-uniform
    __syncthreads();

    const float* ep = emb + (size_t)img * C * INTER + q;
    float u[HID];
    #pragma unroll
    for (int k = 0; k < HID; k++) u[k] = 0.f;
    #pragma unroll
    for (int c = 0; c < C; c++) {
        float ev = ep[c * INTER];
        #pragma unroll
        for (int k = 0; k < HID; k++) u[k] = fmaf(ev, W1[c * HID + k], u[k]);
    }
    int g = gt[img * INTER + q];
    #pragma unroll 4
    for (int n = 0; n < NI; n++) {
        const float* vn = vimg + n * HID;
        float lg0 = b2v, lg1 = 0.f, lg2 = 0.f, lg3 = 0.f;
        #pragma unroll
        for (int k = 0; k < HID; k += 4) {
            lg0 = fmaf(fmaxf(vn[k + 0] - u[k + 0], 0.f), W2[k + 0], lg0);
            lg1 = fmaf(fmaxf(vn[k + 1] - u[k + 1], 0.f), W2[k + 1], lg1);
            lg2 = fmaf(fmaxf(vn[k + 2] - u[k + 2], 0.f), W2[k + 2], lg2);
            lg3 = fmaf(fmaxf(vn[k + 3] - u[k + 3], 0.f), W2[k + 3], lg3);
        }
        float lg = (lg0 + lg1) + (lg2 + lg3);
        bool pos = (g == n + 1);
        float err = pos ? (1.f - lg) : (1.f + lg);
        int bn = (int)((emax - err) * invbw);
        bn = bn < 0 ? 0 : (bn >= NBINS ? NBINS - 1 : bn);
        atomicAdd(&sm.h[bn], pos ? 0x10001u : 1u);
    }
    __syncthreads();
    unsigned long long* f64 = (unsigned long long*)(wsu + OFF_F64) + (size_t)img * NBINS;
    for (int i = tid; i < NBINS; i += THR) {
        unsigned pk = sm.h[i];
        if (pk)
            atomicAdd(&f64[i], (unsigned long long)(pk & 0xFFFFu)
                             | ((unsigned long long)(pk >> 16) << 32));
    }

    // ---- last-block detection
    __threadfence();
    __syncthreads();
    if (tid == 0)
        s_last = (atomicAdd(&wsu[OFF_DONE1 + img], 1u) == (unsigned)(BPI - 1));
    __syncthreads();
    if (!s_last) return;

    // ---- loss tail: one block per image, histogram guaranteed complete
    {
        const int T = THR, CHUNK = NBINS / THR;   // 8
        int im = img;
        float bw = (emax - emin) / (float)NBINS;
        for (int i = tid; i < NBINS; i += T) {
            unsigned long long pk = aload_u64(&f64[i]);
            unsigned cv = (unsigned)(pk & 0xFFFFFFFFu);
            sm.ls.cnt[i] = cv;
            sm.ls.pos[i] = (unsigned)(pk >> 32);
            float center = emax - ((float)i + 0.5f) * bw;
            sm.ls.sum[i] = (float)cv * fmaxf(center, 0.f);
        }
        __syncthreads();
        // pad-region: exact error values, PADMULT each, label 0
        if (tid < NI) {
            float pe = ws[OFF_PERR + im * NI + tid];   // written prior kernel
            int bn = (int)((emax - pe) * invbw);
            bn = bn < 0 ? 0 : (bn >= NBINS ? NBINS - 1 : bn);
            atomicAdd(&sm.ls.cnt[bn], (unsigned)PADMULT);
            atomicAdd(&sm.ls.sum[bn], (float)PADMULT * fmaxf(pe, 0.f));
        }
        __syncthreads();
        unsigned ccnt = 0, cpos = 0;
        for (int j = 0; j < CHUNK; j++) {
            int bn = tid * CHUNK + j;
            ccnt += sm.ls.cnt[bn]; cpos += sm.ls.pos[bn];
        }
        sm.ls.pc[tid] = ccnt; sm.ls.pp[tid] = cpos;
        __syncthreads();
        for (int off = 1; off < T; off <<= 1) {
            unsigned ac = 0, ap = 0;
            if (tid >= off) { ac = sm.ls.pc[tid - off]; ap = sm.ls.pp[tid - off]; }
            __syncthreads();
            sm.ls.pc[tid] += ac; sm.ls.pp[tid] += ap;
            __syncthreads();
        }
        double Gd = (double)sm.ls.pp[T - 1];
        double r = (double)(sm.ls.pc[tid] - ccnt);
        double L = (double)(sm.ls.pp[tid] - cpos);
        double Jprev = 1.0 - (Gd - L) / (Gd + r - L);
        double acc = 0.0;
        for (int j = 0; j < CHUNK; j++) {
            int bn = tid * CHUNK + j;
            unsigned cv = sm.ls.cnt[bn], pv = sm.ls.pos[bn];
            if (cv) {
                r += (double)cv; L += (double)pv;
                double J = 1.0 - (Gd - L) / (Gd + r - L);
                double mean = (double)sm.ls.sum[bn] / (double)cv;
                acc += mean * (J - Jprev);
                Jprev = J;
            }
        }
        sm.ls.a[tid] = acc;
        __syncthreads();
        for (int s = T / 2; s > 0; s >>= 1) {
            if (tid < s) sm.ls.a[tid] += sm.ls.a[tid + s];
            __syncthreads();
        }
        if (tid == 0) atomicAdd(out, (float)(sm.ls.a[0] * 0.25));  // mean over B=4
    }
}

extern "C" void kernel_launch(void* const* d_in, const int* in_sizes, int n_in,
                              void* d_out, int out_size, void* d_ws, size_t ws_size,
                              hipStream_t stream) {
    const float* emb = (const float*)d_in[0];
    const float* wgt = (const float*)d_in[1];
    const int*   gt  = (const int*)d_in[2];
    const float* W1  = (const float*)d_in[3];
    const float* b1  = (const float*)d_in[4];
    const float* W2  = (const float*)d_in[5];
    const float* b2  = (const float*)d_in[6];
    float* out = (float*)d_out;
    float* ws  = (float*)d_ws;
    unsigned* wsu = (unsigned*)d_ws;

    k_init<<<INIT_BLK, 256, 0, stream>>>(wsu, out);
    k_stats<<<NBLK, THR, 0, stream>>>(emb, wgt, gt, W1, b1, W2, b2, ws, wsu);
    k_hist<<<NBLK, THR, 0, stream>>>(emb, gt, W1, W2, b2, ws, wsu, out);
}

// Round 8
// 137.712 us; speedup vs baseline: 1.3450x; 1.3450x over previous
//
#include <hip/hip_runtime.h>

#define NBINS 2048
#define B 4
#define C 16
#define HID 32
#define NI 32
#define INTER 36864           // 192*192 interior pixels per image
#define PADMULT 28672         // 256*256 - 192*192 padded pixels per instance
#define EPSF 1e-6f
#define THR 256
#define BPI 144               // blocks per image, 1 pixel/thread
#define NBLK (B * BPI)        // 576 blocks
#define INIT_BLK 64

// ---- ws layout (uint units)
#define OFF_COUNTS 0                      // [B][NI] float
#define OFF_CSUMS  (OFF_COUNTS + B*NI)    // [B][NI][C] float
#define OFF_V      (OFF_CSUMS + B*NI*C)   // [B][NI][HID] float
#define OFF_PERR   (OFF_V + B*NI*HID)     // [B][NI] float
#define OFF_MKEY   (OFF_PERR + B*NI)      // [B] uint: fmap(max ||e||^2)
#define OFF_RANGE  (OFF_MKEY + B)         // [B][2] float: emin, emax
#define OFF_DONE0  (OFF_RANGE + 2*B)      // [B] uint: stats blocks done
#define OFF_DONE1  (OFF_DONE0 + B)        // [B] uint: hist blocks done
#define CTRL_END   (OFF_DONE1 + B)
#define OFF_F64    8192                   // [B][NBINS] u64 (cnt lo32 | pos hi32)

__device__ inline unsigned fmap(float f) {
    unsigned u = __float_as_uint(f);
    return (u & 0x80000000u) ? ~u : (u | 0x80000000u);
}
__device__ inline float funmap(unsigned k) {
    return (k & 0x80000000u) ? __uint_as_float(k & 0x7fffffffu)
                             : __uint_as_float(~k);
}
// Agent-scope atomic loads: consumer side of the last-block pattern.
__device__ inline float aload_f(const float* p) {
    return __hip_atomic_load(p, __ATOMIC_RELAXED, __HIP_MEMORY_SCOPE_AGENT);
}
__device__ inline unsigned aload_u(const unsigned* p) {
    return __hip_atomic_load(p, __ATOMIC_RELAXED, __HIP_MEMORY_SCOPE_AGENT);
}
__device__ inline unsigned long long aload_u64(const unsigned long long* p) {
    return __hip_atomic_load(p, __ATOMIC_RELAXED, __HIP_MEMORY_SCOPE_AGENT);
}
// R8: release edge for the last-block pattern. All producer values on
// this edge are DEVICE-SCOPE ATOMICS (already performed at the coherent
// point -- that is what makes them atomic across XCDs). So the only
// requirement is completion-ordering: my atomics acked before my DONE
// increment. s_waitcnt vmcnt(0) gives that per-wave; __syncthreads()
// extends it block-wide. __threadfence() additionally did buffer_wbl2 +
// buffer_inv (L2 writeback+invalidate) PER BLOCK x 576 -- that cache
// maintenance (needed only to publish PLAIN stores, of which this edge
// has none) cost ~25-30us per dispatch in R5/R7.
__device__ inline void release_atomics() {
    asm volatile("s_waitcnt vmcnt(0)" ::: "memory");
}

// k_init: zero control words + F64 histogram + out. 64 blocks, ~2 us.
__global__ void k_init(unsigned* wsu, float* out) {
    unsigned gtid = blockIdx.x * 256u + threadIdx.x;
    for (unsigned i = gtid; i < CTRL_END; i += INIT_BLK * 256u) wsu[i] = 0u;
    unsigned* f = wsu + OFF_F64;
    for (unsigned i = gtid; i < B * NBINS * 2; i += INIT_BLK * 256u) f[i] = 0u;
    if (gtid == 0) out[0] = 0.f;
}

// k_stats: per-instance counts & weighted embedding sums + max ||e||^2,
// then the LAST block of each image computes centers/V/range inline.
__global__ __launch_bounds__(THR, 4) void k_stats(
        const float* __restrict__ emb, const float* __restrict__ wgt,
        const int* __restrict__ gt, const float* __restrict__ W1,
        const float* __restrict__ b1, const float* __restrict__ W2,
        const float* __restrict__ b2, float* ws, unsigned* wsu) {
    struct SSt { float cnt[NI]; float sum[NI * 17]; };  // stride 17: bank split
    struct SCt { float v[NI * HID]; float a[HID]; float stage[NI * (C + 1)]; };
    __shared__ union { SSt st; SCt ct; } sm;
    __shared__ unsigned s_mk, s_lo, s_hi;
    __shared__ int s_last;
    int tid = threadIdx.x, bx = blockIdx.x;
    int img = bx / BPI;
    int q = (bx - img * BPI) * THR + tid;
    for (int i = tid; i < NI; i += THR) sm.st.cnt[i] = 0.f;
    for (int i = tid; i < NI * 17; i += THR) sm.st.sum[i] = 0.f;
    if (tid == 0) s_mk = 0u;
    __syncthreads();

    int g = gt[img * INTER + q];
    const float* ep = emb + (size_t)img * C * INTER + q;
    float e[C];
    float nrm = 0.f;
    #pragma unroll
    for (int c = 0; c < C; c++) { e[c] = ep[c * INTER]; nrm = fmaf(e[c], e[c], nrm); }
    if (g > 0) {
        float wv = wgt[img * INTER + q];
        atomicAdd(&sm.st.cnt[g - 1], wv);
        #pragma unroll
        for (int c = 0; c < C; c++)
            atomicAdd(&sm.st.sum[(g - 1) * 17 + c], e[c] * wv);
    }
    atomicMax(&s_mk, fmap(nrm));
    __syncthreads();
    for (int i = tid; i < NI; i += THR)
        atomicAdd(&ws[OFF_COUNTS + img * NI + i], sm.st.cnt[i]);
    for (int i = tid; i < NI * C; i += THR) {
        int n = i / C, c = i - n * C;
        atomicAdd(&ws[OFF_CSUMS + (img * NI + n) * C + c], sm.st.sum[n * 17 + c]);
    }
    if (tid == 0) atomicMax(&wsu[OFF_MKEY + img], s_mk);

    // ---- last-block detection (release: atomics acked, no cache maint)
    release_atomics();
    __syncthreads();
    if (tid == 0)
        s_last = (atomicAdd(&wsu[OFF_DONE0 + img], 1u) == (unsigned)(BPI - 1));
    __syncthreads();
    if (!s_last) return;

    // ---- centers tail: one block per image, stats guaranteed complete
    int im = img;
    for (int i = tid; i < NI * (C + 1); i += THR) {
        float v = (i < NI) ? aload_f(&ws[OFF_COUNTS + im * NI + i])
                           : aload_f(&ws[OFF_CSUMS + im * NI * C + (i - NI)]);
        sm.ct.stage[i] = v;   // [0,NI) counts, [NI..) csums row-major
    }
    float b2v = b2[0];
    float M = sqrtf(funmap(aload_u(&wsu[OFF_MKEY + im])));
    if (tid < HID) {
        float ssq = 0.f;
        #pragma unroll
        for (int c = 0; c < C; c++)
            ssq = fmaf(W1[c * HID + tid], W1[c * HID + tid], ssq);
        sm.ct.a[tid] = M * sqrtf(ssq);
    }
    if (tid == 0) { s_lo = 0xFFFFFFFFu; s_hi = 0u; }
    __syncthreads();
    for (int idx = tid; idx < NI * HID; idx += THR) {
        int n = idx >> 5, k = idx & 31;
        float cv = sm.ct.stage[n] + EPSF;
        float acc = b1[k];
        #pragma unroll
        for (int c = 0; c < C; c++)
            acc += (sm.ct.stage[NI + n * C + c] / cv) * W1[c * HID + k];
        sm.ct.v[idx] = acc;
        ws[OFF_V + im * NI * HID + idx] = acc;   // next-kernel visibility
    }
    __syncthreads();
    if (tid < NI) {
        float lo = b2v, hi = b2v, lgp = b2v;
        #pragma unroll
        for (int k = 0; k < HID; k++) {
            float vk = sm.ct.v[tid * HID + k], a = sm.ct.a[k], w = W2[k];
            float thi = fmaxf(vk + a, 0.f), tlo = fmaxf(vk - a, 0.f);
            hi += w * (w > 0.f ? thi : tlo);
            lo += w * (w > 0.f ? tlo : thi);
            lgp = fmaf(fmaxf(vk, 0.f), w, lgp);   // pad pixels: u = 0 exact
        }
        float pe = 1.f + lgp;
        ws[OFF_PERR + im * NI + tid] = pe;
        atomicMin(&s_lo, fmap(fminf(1.f - hi, 1.f + lo)));
        atomicMax(&s_hi, fmap(fmaxf(1.f - lo, 1.f + hi)));
    }
    __syncthreads();
    if (tid == 0) {
        ((float*)wsu)[OFF_RANGE + im * 2]     = funmap(s_lo);
        ((float*)wsu)[OFF_RANGE + im * 2 + 1] = funmap(s_hi);
    }
}

// k_hist: vn[] via wave-uniform scalar loads (SMEM pipe); LDS histogram;
// u64 atomic flush; LAST block per image runs the Lovasz loss inline.
struct SMemLoss { unsigned cnt[NBINS]; unsigned pos[NBINS]; float sum[NBINS];
                  unsigned pc[THR]; unsigned pp[THR]; double a[THR]; };

__global__ __launch_bounds__(THR, 4) void k_hist(
        const float* __restrict__ emb, const int* __restrict__ gt,
        const float* __restrict__ W1, const float* __restrict__ W2,
        const float* __restrict__ b2, const float* __restrict__ ws,
        unsigned* wsu, float* out) {
    __shared__ union { unsigned h[NBINS]; SMemLoss ls; } sm;   // 28 KB
    __shared__ int s_last;
    int tid = threadIdx.x, bx = blockIdx.x;
    int img = bx / BPI;
    int q = (bx - img * BPI) * THR + tid;
    for (int i = tid; i < NBINS; i += THR) sm.h[i] = 0u;
    float emin = ((const float*)wsu)[OFF_RANGE + img * 2];
    float emax = ((const float*)wsu)[OFF_RANGE + img * 2 + 1];
    float invbw = (float)NBINS / fmaxf(emax - emin, 1e-20f);
    float b2v = b2[0];
    const float* vimg = ws + OFF_V + img * NI * HID;   // wave-uniform
    __syncthreads();

    const float* ep = emb + (size_t)img * C * INTER + q;
    float u[HID];
    #pragma unroll
    for (int k = 0; k < HID; k++) u[k] = 0.f;
    #pragma unroll
    for (int c = 0; c < C; c++) {
        float ev = ep[c * INTER];
        #pragma unroll
        for (int k = 0; k < HID; k++) u[k] = fmaf(ev, W1[c * HID + k], u[k]);
    }
    int g = gt[img * INTER + q];
    #pragma unroll 4
    for (int n = 0; n < NI; n++) {
        const float* vn = vimg + n * HID;
        float lg0 = b2v, lg1 = 0.f, lg2 = 0.f, lg3 = 0.f;
        #pragma unroll
        for (int k = 0; k < HID; k += 4) {
            lg0 = fmaf(fmaxf(vn[k + 0] - u[k + 0], 0.f), W2[k + 0], lg0);
            lg1 = fmaf(fmaxf(vn[k + 1] - u[k + 1], 0.f), W2[k + 1], lg1);
            lg2 = fmaf(fmaxf(vn[k + 2] - u[k + 2], 0.f), W2[k + 2], lg2);
            lg3 = fmaf(fmaxf(vn[k + 3] - u[k + 3], 0.f), W2[k + 3], lg3);
        }
        float lg = (lg0 + lg1) + (lg2 + lg3);
        bool pos = (g == n + 1);
        float err = pos ? (1.f - lg) : (1.f + lg);
        int bn = (int)((emax - err) * invbw);
        bn = bn < 0 ? 0 : (bn >= NBINS ? NBINS - 1 : bn);
        atomicAdd(&sm.h[bn], pos ? 0x10001u : 1u);
    }
    __syncthreads();
    unsigned long long* f64 = (unsigned long long*)(wsu + OFF_F64) + (size_t)img * NBINS;
    for (int i = tid; i < NBINS; i += THR) {
        unsigned pk = sm.h[i];
        if (pk)
            atomicAdd(&f64[i], (unsigned long long)(pk & 0xFFFFu)
                             | ((unsigned long long)(pk >> 16) << 32));
    }

    // ---- last-block detection (release: atomics acked, no cache maint)
    release_atomics();
    __syncthreads();
    if (tid == 0)
        s_last = (atomicAdd(&wsu[OFF_DONE1 + img], 1u) == (unsigned)(BPI - 1));
    __syncthreads();
    if (!s_last) return;

    // ---- loss tail: one block per image, histogram guaranteed complete
    {
        const int T = THR, CHUNK = NBINS / THR;   // 8
        int im = img;
        float bw = (emax - emin) / (float)NBINS;
        for (int i = tid; i < NBINS; i += T) {
            unsigned long long pk = aload_u64(&f64[i]);
            unsigned cv = (unsigned)(pk & 0xFFFFFFFFu);
            sm.ls.cnt[i] = cv;
            sm.ls.pos[i] = (unsigned)(pk >> 32);
            float center = emax - ((float)i + 0.5f) * bw;
            sm.ls.sum[i] = (float)cv * fmaxf(center, 0.f);
        }
        __syncthreads();
        // pad-region: exact error values, PADMULT each, label 0
        if (tid < NI) {
            float pe = ws[OFF_PERR + im * NI + tid];   // written prior kernel
            int bn = (int)((emax - pe) * invbw);
            bn = bn < 0 ? 0 : (bn >= NBINS ? NBINS - 1 : bn);
            atomicAdd(&sm.ls.cnt[bn], (unsigned)PADMULT);
            atomicAdd(&sm.ls.sum[bn], (float)PADMULT * fmaxf(pe, 0.f));
        }
        __syncthreads();
        unsigned ccnt = 0, cpos = 0;
        for (int j = 0; j < CHUNK; j++) {
            int bn = tid * CHUNK + j;
            ccnt += sm.ls.cnt[bn]; cpos += sm.ls.pos[bn];
        }
        sm.ls.pc[tid] = ccnt; sm.ls.pp[tid] = cpos;
        __syncthreads();
        for (int off = 1; off < T; off <<= 1) {
            unsigned ac = 0, ap = 0;
            if (tid >= off) { ac = sm.ls.pc[tid - off]; ap = sm.ls.pp[tid - off]; }
            __syncthreads();
            sm.ls.pc[tid] += ac; sm.ls.pp[tid] += ap;
            __syncthreads();
        }
        double Gd = (double)sm.ls.pp[T - 1];
        double r = (double)(sm.ls.pc[tid] - ccnt);
        double L = (double)(sm.ls.pp[tid] - cpos);
        double Jprev = 1.0 - (Gd - L) / (Gd + r - L);
        double acc = 0.0;
        for (int j = 0; j < CHUNK; j++) {
            int bn = tid * CHUNK + j;
            unsigned cv = sm.ls.cnt[bn], pv = sm.ls.pos[bn];
            if (cv) {
                r += (double)cv; L += (double)pv;
                double J = 1.0 - (Gd - L) / (Gd + r - L);
                double mean = (double)sm.ls.sum[bn] / (double)cv;
                acc += mean * (J - Jprev);
                Jprev = J;
            }
        }
        sm.ls.a[tid] = acc;
        __syncthreads();
        for (int s = T / 2; s > 0; s >>= 1) {
            if (tid < s) sm.ls.a[tid] += sm.ls.a[tid + s];
            __syncthreads();
        }
        if (tid == 0) atomicAdd(out, (float)(sm.ls.a[0] * 0.25));  // mean over B=4
    }
}

extern "C" void kernel_launch(void* const* d_in, const int* in_sizes, int n_in,
                              void* d_out, int out_size, void* d_ws, size_t ws_size,
                              hipStream_t stream) {
    const float* emb = (const float*)d_in[0];
    const float* wgt = (const float*)d_in[1];
    const int*   gt  = (const int*)d_in[2];
    const float* W1  = (const float*)d_in[3];
    const float* b1  = (const float*)d_in[4];
    const float* W2  = (const float*)d_in[5];
    const float* b2  = (const float*)d_in[6];
    float* out = (float*)d_out;
    float* ws  = (float*)d_ws;
    unsigned* wsu = (unsigned*)d_ws;

    k_init<<<INIT_BLK, 256, 0, stream>>>(wsu, out);
    k_stats<<<NBLK, THR, 0, stream>>>(emb, wgt, gt, W1, b1, W2, b2, ws, wsu);
    k_hist<<<NBLK, THR, 0, stream>>>(emb, gt, W1, W2, b2, ws, wsu, out);
}